// Round 11
// baseline (135.599 us; speedup 1.0000x reference)
//
#include <hip/hip_runtime.h>
#include <math.h>

#define K 3
#define K2 9
#define BB 4
#define C 64
#define H 128
#define W 128
#define O 64
#define HW (H*W)
#define Ho 128
#define Wo 128
#define TILE 64        // pixels per block (along w)

typedef _Float16 half4v __attribute__((ext_vector_type(4)));
typedef _Float16 half8v __attribute__((ext_vector_type(8)));
typedef float float4v __attribute__((ext_vector_type(4)));

__device__ __forceinline__ half8v bcast8(_Float16 w) {
    half8v v = {w, w, w, w, w, w, w, w};
    return v;
}

// ---------------------------------------------------------------------------
// prep_all: blocks [0, BB*H) build xh (NCHW fp32 -> NHWC fp16, LDS transpose);
// blocks [BB*H, BB*H+144) pack MFMA weight fragments, TAP-MAJOR K:
//  wB : [tap*2+s][ot(4)][lane(64)][jj(8)]  o = ot*16+(lane&15), ch = s*32+quad*8+jj
//  wAB: [tap*2+s][jt(2)][lane(64)][jj(8)]  n = jt*16+(lane&15) in 0..26
// These bytes serve as the MFMA **A** operand (m = o/n-channel, k = ch):
// A-layout (m=lane&15, k=quad*8+j) == B-layout (n=lane&15, k=quad*8+j),
// both verified on-HW in earlier rounds of this kernel.
// ---------------------------------------------------------------------------
__global__ __launch_bounds__(256) void prep_all(
    const float* __restrict__ x,
    const float* __restrict__ weight,
    const float* __restrict__ offset_w,
    const float* __restrict__ mod_w,
    _Float16* __restrict__ xh,
    _Float16* __restrict__ wB,
    _Float16* __restrict__ wAB)
{
    int t = threadIdx.x;
    if (blockIdx.x < BB * H) {
        __shared__ _Float16 tile[W][68];     // x-pos x channel (pad 68)
        int by = blockIdx.x;
        int y = by % H, b = by / H;
        int xq = t & 31, cr = t >> 5;        // xq: float4 index, cr: 0..7
        #pragma unroll
        for (int g = 0; g < 8; g++) {
            int c = g * 8 + cr;
            float4v v = *(const float4v*)&x[(((size_t)b * C + c) * H + y) * W + xq * 4];
            tile[xq * 4 + 0][c] = (_Float16)v[0];
            tile[xq * 4 + 1][c] = (_Float16)v[1];
            tile[xq * 4 + 2][c] = (_Float16)v[2];
            tile[xq * 4 + 3][c] = (_Float16)v[3];
        }
        __syncthreads();
        int xp2 = t >> 1, hf = t & 1;        // each thread writes 32 ch = 64 B
        const _Float16* src = &tile[xp2][hf * 32];
        _Float16* dst = xh + (((size_t)b * H + y) * W + xp2) * 64 + hf * 32;
        #pragma unroll
        for (int i = 0; i < 8; i++)
            *(half4v*)(dst + i * 4) = *(const half4v*)(src + i * 4);
    } else {
        int i = (blockIdx.x - BB * H) * 256 + t;
        if (i < K2 * 2 * 4 * 64 * 8) {          // 36864
            int jj = i & 7;
            int lane = (i >> 3) & 63;
            int q4 = (i >> 9) & 3;
            int i2 = i >> 11;                    // tap*2 + s, [0,18)
            int tap = i2 >> 1, s = i2 & 1;
            int ch = s * 32 + ((lane >> 4) & 3) * 8 + jj;
            int o = q4 * 16 + (lane & 15);
            wB[i] = (_Float16)weight[(o * C + ch) * 9 + tap];
        }
        if (i < K2 * 2 * 2 * 64 * 8) {          // 18432
            int jj = i & 7;
            int lane = (i >> 3) & 63;
            int jt = (i >> 9) & 1;
            int i2 = i >> 10;                    // tap*2 + s
            int tap = i2 >> 1, s = i2 & 1;
            int ch = s * 32 + ((lane >> 4) & 3) * 8 + jj;
            int n = jt * 16 + (lane & 15);
            float wv = 0.f;
            if (n < 27)
                wv = (n < 18) ? offset_w[(n * C + ch) * 9 + tap]
                              : mod_w[((n - 18) * C + ch) * 9 + tap];
            wAB[i] = (_Float16)wv;
        }
    }
}

// ---------------------------------------------------------------------------
// fused_kernel: one block per (b,h,64px strip), 256 threads, 4 waves.
// SWAPPED MFMA operands: A = weights (m = output channel), B = samples
// (n = pixel). Lane (px=lane&15, k-seg=quad) loads its pixel's 8 consecutive
// channels straight from HWC xh into the B-fragment — gather feeds MFMA
// through REGISTERS ONLY. No staging LDS, no tap barriers (2 barriers total),
// no epilogue transpose. Wave q owns px-tile q; loops o-tiles via A.
// ---------------------------------------------------------------------------
__global__ __launch_bounds__(256) void fused_kernel(
    const _Float16* __restrict__ xh,
    const _Float16* __restrict__ wB,
    const _Float16* __restrict__ wAB,
    const float* __restrict__ bias,
    const float* __restrict__ offset_b,
    const float* __restrict__ mod_b,
    float* __restrict__ out)
{
    __shared__ unsigned int s_ai[K2 * TILE];    // 2,304 B (a00 | dx<<14 | dy<<15)
    __shared__ half4v s_wgt[K2 * TILE];         // 4,608 B (fp16 corner products)
    __shared__ float s_res[27 * 65];            // 7,020 B (offset/mod conv result)
    __shared__ float s_mm[TILE];                //   256 B   => 14.2 KB total

    // XCD-aware swizzle: each XCD gets a contiguous 64-row h-band of one image.
    int blk = blockIdx.x;
    int xcd = blk & 7, idx = blk >> 3;
    int b  = xcd >> 1;
    int h  = ((xcd & 1) << 6) | (idx >> 1);
    int wt = idx & 1;
    int t  = threadIdx.x;
    int q  = t >> 6;                            // wave index = px-tile
    int lane = t & 63;
    int m16 = lane & 15;
    int quad = (lane >> 4) & 3;
    int w0 = wt * TILE;
    int pxg = q * 16 + m16;                     // this lane's pixel (MFMA col n)
    int chq = quad * 8;                         // k-offset within a 32-step

    const _Float16* xb = xh + (size_t)b * HW * 64;

    // ================= phase A: offset/mod conv (registers only) ============
    float4v acc2[2];
    #pragma unroll
    for (int jt = 0; jt < 2; jt++) { float4v z = {0.f,0.f,0.f,0.f}; acc2[jt] = z; }

    #pragma unroll 3
    for (int tap = 0; tap < K2; tap++) {
        int ki = tap / 3, kj = tap % 3;
        int y = h + ki - 1;
        int xv = w0 + pxg + kj - 1;
        _Float16 m = (_Float16)(((y >= 0 && y < H) ? 1.f : 0.f) *
                                ((xv >= 0 && xv < W) ? 1.f : 0.f));
        int yc = min(max(y, 0), H - 1), xc = min(max(xv, 0), W - 1);
        const _Float16* src = xb + ((size_t)(yc * W + xc)) * 64 + chq;
        half8v vm = bcast8(m);
        half8v b0 = *(const half8v*)src * vm;          // s=0: ch chq..chq+7
        half8v b1 = *(const half8v*)(src + 32) * vm;   // s=1: ch 32+chq..
        #pragma unroll
        for (int jt = 0; jt < 2; jt++) {
            half8v a0 = *(const half8v*)(wAB + (((tap * 2 + 0) * 2 + jt) * 64 + lane) * 8);
            half8v a1 = *(const half8v*)(wAB + (((tap * 2 + 1) * 2 + jt) * 64 + lane) * 8);
            acc2[jt] = __builtin_amdgcn_mfma_f32_16x16x32_f16(a0, b0, acc2[jt], 0, 0, 0);
            acc2[jt] = __builtin_amdgcn_mfma_f32_16x16x32_f16(a1, b1, acc2[jt], 0, 0, 0);
        }
    }
    // C layout (swapped): col = pxg, row = n-channel = jt*16 + quad*4 + r
    #pragma unroll
    for (int jt = 0; jt < 2; jt++) {
        #pragma unroll
        for (int r = 0; r < 4; r++) {
            int n = jt * 16 + quad * 4 + r;
            if (n < 27) s_res[n * 65 + pxg] = acc2[jt][r];
        }
    }
    __syncthreads();

    // ================= phase B: bilinear params + modmean =================
    #pragma unroll
    for (int ee = 0; ee < 3; ee++) {
        int e = t + ee * 256;
        if (e < K2 * TILE) {
            int k = e >> 6, p = e & 63;
            float offy = s_res[k * 65 + p] + offset_b[k];
            float offx = s_res[(9 + k) * 65 + p] + offset_b[9 + k];
            float sy = (float)(h + k / 3 - 1) + offy;
            float sx = (float)(w0 + p + k % 3 - 1) + offx;
            float fy = floorf(sy), fx = floorf(sx);
            int y0 = (int)fy, x0 = (int)fx;
            float wy1 = sy - fy, wx1 = sx - fx;
            int y0c = min(max(y0, 0), H - 1), y1c = min(max(y0 + 1, 0), H - 1);
            int x0c = min(max(x0, 0), W - 1), x1c = min(max(x0 + 1, 0), W - 1);
            s_ai[e] = (unsigned int)(y0c * W + x0c)
                    | ((unsigned int)(x1c - x0c) << 14)
                    | ((unsigned int)(y1c - y0c) << 15);
            float wg0 = (1.f - wy1) * ((y0 >= 0 && y0 < H) ? 1.f : 0.f);
            float wg1 = wy1 * ((y0 + 1 >= 0 && y0 + 1 < H) ? 1.f : 0.f);
            float wg2 = (1.f - wx1) * ((x0 >= 0 && x0 < W) ? 1.f : 0.f);
            float wg3 = wx1 * ((x0 + 1 >= 0 && x0 + 1 < W) ? 1.f : 0.f);
            half4v wp4;
            wp4[0] = (_Float16)(wg0 * wg2);   // (y0,x0)
            wp4[1] = (_Float16)(wg0 * wg3);   // (y0,x1)
            wp4[2] = (_Float16)(wg1 * wg2);   // (y1,x0)
            wp4[3] = (_Float16)(wg1 * wg3);   // (y1,x1)
            s_wgt[e] = wp4;
        }
    }
    if (t < TILE) {
        float sm = 0.f;
        #pragma unroll
        for (int m = 0; m < 9; m++) {
            float z = s_res[(18 + m) * 65 + t] + mod_b[m];
            sm += 1.f / (1.f + expf(-z));
        }
        s_mm[t] = sm * (1.f / 9.f);
    }
    __syncthreads();

    // ================= phase C: gather -> registers -> MFMA =================
    float4v acc[4];
    #pragma unroll
    for (int i = 0; i < 4; i++) { float4v z = {0.f,0.f,0.f,0.f}; acc[i] = z; }

    #pragma unroll 3
    for (int tap = 0; tap < K2; tap++) {
        int e = tap * 64 + pxg;
        unsigned int ai = s_ai[e];
        half4v wg = s_wgt[e];
        int a00 = ai & 0x3FFF;
        int dxo = ((ai >> 14) & 1) * 64;
        int dyo = ((ai >> 15) & 1) * (W * 64);
        const _Float16* base = xb + (size_t)a00 * 64 + chq;
        half8v vw0 = bcast8(wg[0]), vw1 = bcast8(wg[1]);
        half8v vw2 = bcast8(wg[2]), vw3 = bcast8(wg[3]);
        half8v b0 = *(const half8v*)(base)             * vw0
                  + *(const half8v*)(base + dxo)       * vw1
                  + *(const half8v*)(base + dyo)       * vw2
                  + *(const half8v*)(base + dyo + dxo) * vw3;
        half8v b1 = *(const half8v*)(base + 32)             * vw0
                  + *(const half8v*)(base + 32 + dxo)       * vw1
                  + *(const half8v*)(base + 32 + dyo)       * vw2
                  + *(const half8v*)(base + 32 + dyo + dxo) * vw3;
        #pragma unroll
        for (int ot = 0; ot < 4; ot++) {
            half8v a0 = *(const half8v*)(wB + (((tap * 2 + 0) * 4 + ot) * 64 + lane) * 8);
            half8v a1 = *(const half8v*)(wB + (((tap * 2 + 1) * 4 + ot) * 64 + lane) * 8);
            acc[ot] = __builtin_amdgcn_mfma_f32_16x16x32_f16(a0, b0, acc[ot], 0, 0, 0);
            acc[ot] = __builtin_amdgcn_mfma_f32_16x16x32_f16(a1, b1, acc[ot], 0, 0, 0);
        }
    }

    // ================= epilogue (no LDS transpose) =================
    // acc[ot]: col = pxg, row = o-in-tile = quad*4 + r
    {
        float mm = s_mm[pxg];
        #pragma unroll
        for (int ot = 0; ot < 4; ot++) {
            float4v bv = *(const float4v*)&bias[ot * 16 + quad * 4];
            #pragma unroll
            for (int r = 0; r < 4; r++) {
                int o = ot * 16 + quad * 4 + r;
                out[(((size_t)b * O + o) * Ho + h) * Wo + w0 + pxg] =
                    acc[ot][r] * mm + bv[r];
            }
        }
    }
}

extern "C" void kernel_launch(void* const* d_in, const int* in_sizes, int n_in,
                              void* d_out, int out_size, void* d_ws, size_t ws_size,
                              hipStream_t stream) {
    const float* x        = (const float*)d_in[0];
    const float* weight   = (const float*)d_in[1];
    const float* bias     = (const float*)d_in[2];
    const float* offset_w = (const float*)d_in[3];
    const float* offset_b = (const float*)d_in[4];
    const float* mod_w    = (const float*)d_in[5];
    const float* mod_b    = (const float*)d_in[6];
    float* out = (float*)d_out;

    // Workspace (halves): wB 36,864 | wAB 18,432 | xh 4,194,304 (byte 110,592)
    _Float16* wB  = (_Float16*)d_ws;
    _Float16* wAB = wB + 36864;
    _Float16* xh  = wAB + 18432;

    prep_all<<<BB * H + 144, 256, 0, stream>>>(
        x, weight, offset_w, mod_w, xh, wB, wAB);

    int nblk = BB * Ho * (Wo / TILE);   // 1024
    fused_kernel<<<nblk, 256, 0, stream>>>(
        xh, wB, wAB, bias, offset_b, mod_b, out);
}

// Round 12
// 112.540 us; speedup vs baseline: 1.2049x; 1.2049x over previous
//
#include <hip/hip_runtime.h>
#include <math.h>

#define K 3
#define K2 9
#define BB 4
#define C 64
#define H 128
#define W 128
#define O 64
#define HW (H*W)
#define Ho 128
#define Wo 128
#define TILE 64        // pixels per block (along w)
#define TSTR 80        // halves per px row in tap tile (160 B, 16B-aligned)

typedef _Float16 half4v __attribute__((ext_vector_type(4)));
typedef _Float16 half8v __attribute__((ext_vector_type(8)));
typedef float float4v __attribute__((ext_vector_type(4)));

__device__ __forceinline__ half8v bcast8(_Float16 w) {
    half8v v = {w, w, w, w, w, w, w, w};
    return v;
}

// ---------------------------------------------------------------------------
// prep_all: blocks [0, BB*H) build xh (NCHW fp32 -> NHWC fp16, LDS transpose);
// blocks [BB*H, BB*H+144) pack MFMA weight fragments, TAP-MAJOR K:
//  wB : [tap*2+s][ot(4)][lane(64)][jj(8)]  o = ot*16+(lane&15), ch = s*32+quad*8+jj
//  wAB: [tap*2+s][jt(2)][lane(64)][jj(8)]  n = jt*16+(lane&15) in 0..26
// Fragment layouts A(m=lane&15,k=quad*8+j) and B(n=lane&15,k=quad*8+j) are
// identical byte-wise — the same packs serve as B (phase C) or A (phase A).
// ---------------------------------------------------------------------------
__global__ __launch_bounds__(256) void prep_all(
    const float* __restrict__ x,
    const float* __restrict__ weight,
    const float* __restrict__ offset_w,
    const float* __restrict__ mod_w,
    _Float16* __restrict__ xh,
    _Float16* __restrict__ wB,
    _Float16* __restrict__ wAB)
{
    int t = threadIdx.x;
    if (blockIdx.x < BB * H) {
        __shared__ _Float16 tile[W][68];     // x-pos x channel (pad 68)
        int by = blockIdx.x;
        int y = by % H, b = by / H;
        int xq = t & 31, cr = t >> 5;        // xq: float4 index, cr: 0..7
        #pragma unroll
        for (int g = 0; g < 8; g++) {
            int c = g * 8 + cr;
            float4v v = *(const float4v*)&x[(((size_t)b * C + c) * H + y) * W + xq * 4];
            tile[xq * 4 + 0][c] = (_Float16)v[0];
            tile[xq * 4 + 1][c] = (_Float16)v[1];
            tile[xq * 4 + 2][c] = (_Float16)v[2];
            tile[xq * 4 + 3][c] = (_Float16)v[3];
        }
        __syncthreads();
        int xp2 = t >> 1, hf = t & 1;        // each thread writes 32 ch = 64 B
        const _Float16* src = &tile[xp2][hf * 32];
        _Float16* dst = xh + (((size_t)b * H + y) * W + xp2) * 64 + hf * 32;
        #pragma unroll
        for (int i = 0; i < 8; i++)
            *(half4v*)(dst + i * 4) = *(const half4v*)(src + i * 4);
    } else {
        int i = (blockIdx.x - BB * H) * 256 + t;
        if (i < K2 * 2 * 4 * 64 * 8) {          // 36864
            int jj = i & 7;
            int lane = (i >> 3) & 63;
            int q4 = (i >> 9) & 3;
            int i2 = i >> 11;                    // tap*2 + s, [0,18)
            int tap = i2 >> 1, s = i2 & 1;
            int ch = s * 32 + ((lane >> 4) & 3) * 8 + jj;
            int o = q4 * 16 + (lane & 15);
            wB[i] = (_Float16)weight[(o * C + ch) * 9 + tap];
        }
        if (i < K2 * 2 * 2 * 64 * 8) {          // 18432
            int jj = i & 7;
            int lane = (i >> 3) & 63;
            int jt = (i >> 9) & 1;
            int i2 = i >> 10;                    // tap*2 + s
            int tap = i2 >> 1, s = i2 & 1;
            int ch = s * 32 + ((lane >> 4) & 3) * 8 + jj;
            int n = jt * 16 + (lane & 15);
            float wv = 0.f;
            if (n < 27)
                wv = (n < 18) ? offset_w[(n * C + ch) * 9 + tap]
                              : mod_w[((n - 18) * C + ch) * 9 + tap];
            wAB[i] = (_Float16)wv;
        }
    }
}

// ---------------------------------------------------------------------------
// fused_kernel: one block per (b,h,64px strip), 256 threads, 4 waves.
// Phase A: REGISTER-ONLY offset/mod conv (r11 structure: A=weights, B=samples
//   loaded per-lane straight from xh) — no LDS, no barriers.
// Phase C: r9 structure — cooperative gather (lane=8px x 8seg: 4 lanes/line,
//   TA-optimal) into block-shared double-buffered tiles; wave q consumes
//   o-tile q so wB is read once per block. 13 barriers total.
// ---------------------------------------------------------------------------
__global__ __launch_bounds__(256) void fused_kernel(
    const _Float16* __restrict__ xh,
    const _Float16* __restrict__ wB,
    const _Float16* __restrict__ wAB,
    const float* __restrict__ bias,
    const float* __restrict__ offset_b,
    const float* __restrict__ mod_b,
    float* __restrict__ out)
{
    __shared__ _Float16 s_T[2][TILE][TSTR];     // 20,480 B (A-tiles; overlays)
    __shared__ unsigned int s_ai[K2 * TILE];    //  2,304 B (a00 | dx<<14 | dy<<15)
    __shared__ half4v s_wgt[K2 * TILE];         //  4,608 B (fp16 corner products)
    __shared__ float s_mm[TILE];                //    256 B   => 27.6 KB
    float* s_res = (float*)&s_T[0][0][0];       // overlay [27][65] (phase A out)
    float* s_out = (float*)&s_T[0][0][0];       // overlay [64][65] (epilogue)

    // XCD-aware swizzle: each XCD gets a contiguous 64-row h-band of one image.
    int blk = blockIdx.x;
    int xcd = blk & 7, idx = blk >> 3;
    int b  = xcd >> 1;
    int h  = ((xcd & 1) << 6) | (idx >> 1);
    int wt = idx & 1;
    int t  = threadIdx.x;
    int q  = t >> 6;                            // wave index
    int lane = t & 63;
    int m16 = lane & 15;
    int quad = (lane >> 4) & 3;
    int w0 = wt * TILE;
    int px = lane;                              // phase-B / epilogue pixel
    int pxg = q * 16 + m16;                     // phase-A lane pixel (B-frag col)
    int chq = quad * 8;                         // k-offset within a 32-step
    int gpx0 = q * 16 + (lane >> 3);            // coop gather: pixel (pg=0)
    int seg  = lane & 7;                        // coop gather: 16B channel segment

    const _Float16* xb = xh + (size_t)b * HW * 64;

    // ========== phase A: offset/mod conv (register-only, r11 verbatim) ======
    float4v acc2[2];
    #pragma unroll
    for (int jt = 0; jt < 2; jt++) { float4v z = {0.f,0.f,0.f,0.f}; acc2[jt] = z; }

    #pragma unroll 3
    for (int tap = 0; tap < K2; tap++) {
        int ki = tap / 3, kj = tap % 3;
        int y = h + ki - 1;
        int xv = w0 + pxg + kj - 1;
        _Float16 m = (_Float16)(((y >= 0 && y < H) ? 1.f : 0.f) *
                                ((xv >= 0 && xv < W) ? 1.f : 0.f));
        int yc = min(max(y, 0), H - 1), xc = min(max(xv, 0), W - 1);
        const _Float16* src = xb + ((size_t)(yc * W + xc)) * 64 + chq;
        half8v vm = bcast8(m);
        half8v b0 = *(const half8v*)src * vm;          // s=0: ch chq..chq+7
        half8v b1 = *(const half8v*)(src + 32) * vm;   // s=1: ch 32+chq..
        #pragma unroll
        for (int jt = 0; jt < 2; jt++) {
            half8v a0 = *(const half8v*)(wAB + (((tap * 2 + 0) * 2 + jt) * 64 + lane) * 8);
            half8v a1 = *(const half8v*)(wAB + (((tap * 2 + 1) * 2 + jt) * 64 + lane) * 8);
            acc2[jt] = __builtin_amdgcn_mfma_f32_16x16x32_f16(a0, b0, acc2[jt], 0, 0, 0);
            acc2[jt] = __builtin_amdgcn_mfma_f32_16x16x32_f16(a1, b1, acc2[jt], 0, 0, 0);
        }
    }
    // C layout (swapped operands): col = pxg, row = n-channel = jt*16+quad*4+r
    #pragma unroll
    for (int jt = 0; jt < 2; jt++) {
        #pragma unroll
        for (int r = 0; r < 4; r++) {
            int n = jt * 16 + quad * 4 + r;
            if (n < 27) s_res[n * 65 + pxg] = acc2[jt][r];
        }
    }
    __syncthreads();

    // ================= phase B: bilinear params + modmean =================
    #pragma unroll
    for (int ee = 0; ee < 3; ee++) {
        int e = t + ee * 256;
        if (e < K2 * TILE) {
            int k = e >> 6, p = e & 63;
            float offy = s_res[k * 65 + p] + offset_b[k];
            float offx = s_res[(9 + k) * 65 + p] + offset_b[9 + k];
            float sy = (float)(h + k / 3 - 1) + offy;
            float sx = (float)(w0 + p + k % 3 - 1) + offx;
            float fy = floorf(sy), fx = floorf(sx);
            int y0 = (int)fy, x0 = (int)fx;
            float wy1 = sy - fy, wx1 = sx - fx;
            int y0c = min(max(y0, 0), H - 1), y1c = min(max(y0 + 1, 0), H - 1);
            int x0c = min(max(x0, 0), W - 1), x1c = min(max(x0 + 1, 0), W - 1);
            s_ai[e] = (unsigned int)(y0c * W + x0c)
                    | ((unsigned int)(x1c - x0c) << 14)
                    | ((unsigned int)(y1c - y0c) << 15);
            float wg0 = (1.f - wy1) * ((y0 >= 0 && y0 < H) ? 1.f : 0.f);
            float wg1 = wy1 * ((y0 + 1 >= 0 && y0 + 1 < H) ? 1.f : 0.f);
            float wg2 = (1.f - wx1) * ((x0 >= 0 && x0 < W) ? 1.f : 0.f);
            float wg3 = wx1 * ((x0 + 1 >= 0 && x0 + 1 < W) ? 1.f : 0.f);
            half4v wp4;
            wp4[0] = (_Float16)(wg0 * wg2);   // (y0,x0)
            wp4[1] = (_Float16)(wg0 * wg3);   // (y0,x1)
            wp4[2] = (_Float16)(wg1 * wg2);   // (y1,x0)
            wp4[3] = (_Float16)(wg1 * wg3);   // (y1,x1)
            s_wgt[e] = wp4;
        }
    }
    if (t < TILE) {
        float sm = 0.f;
        #pragma unroll
        for (int m = 0; m < 9; m++) {
            float z = s_res[(18 + m) * 65 + t] + mod_b[m];
            sm += 1.f / (1.f + expf(-z));
        }
        s_mm[t] = sm * (1.f / 9.f);
    }
    __syncthreads();   // s_res dead; params visible -> tiles reusable

    // ====== phase C: coop gather + shared tiles + MFMA (r9 verbatim) =======
    float4v acc[4];
    #pragma unroll
    for (int i = 0; i < 4; i++) { float4v z = {0.f,0.f,0.f,0.f}; acc[i] = z; }

    // prologue: gather tap 0 -> buf 0
    #pragma unroll
    for (int pg = 0; pg < 2; pg++) {
        int ppx = gpx0 + pg * 8;
        unsigned int ai = s_ai[ppx];             // tap 0
        half4v wg = s_wgt[ppx];
        int a00 = ai & 0x3FFF;
        int dxo = ((ai >> 14) & 1) * 64;
        int dyo = ((ai >> 15) & 1) * (W * 64);
        const _Float16* base = xb + (size_t)a00 * 64 + seg * 8;
        half8v r00 = *(const half8v*)(base);
        half8v r01 = *(const half8v*)(base + dxo);
        half8v r10 = *(const half8v*)(base + dyo);
        half8v r11 = *(const half8v*)(base + dyo + dxo);
        half8v v = r00 * bcast8(wg[0]) + r01 * bcast8(wg[1])
                 + r10 * bcast8(wg[2]) + r11 * bcast8(wg[3]);
        *(half8v*)&s_T[0][ppx][seg * 8] = v;
    }
    __syncthreads();

    #pragma unroll 1
    for (int tap = 0; tap < K2; tap++) {
        half8v rr[2][4]; half4v wgp[2];
        if (tap < 8) {
            #pragma unroll
            for (int pg = 0; pg < 2; pg++) {
                int e = (tap + 1) * 64 + gpx0 + pg * 8;
                unsigned int ai = s_ai[e];
                wgp[pg] = s_wgt[e];
                int a00 = ai & 0x3FFF;
                int dxo = ((ai >> 14) & 1) * 64;
                int dyo = ((ai >> 15) & 1) * (W * 64);
                const _Float16* base = xb + (size_t)a00 * 64 + seg * 8;
                rr[pg][0] = *(const half8v*)(base);
                rr[pg][1] = *(const half8v*)(base + dxo);
                rr[pg][2] = *(const half8v*)(base + dyo);
                rr[pg][3] = *(const half8v*)(base + dyo + dxo);
            }
        }
        #pragma unroll
        for (int s = 0; s < 2; s++) {
            int widx = (((tap * 2 + s) * 4 + q) * 64 + lane) * 8;
            half8v bf = *(const half8v*)(wB + widx);
            #pragma unroll
            for (int i = 0; i < 4; i++) {
                half8v af = *(const half8v*)&s_T[tap & 1][i * 16 + m16][s * 32 + quad * 8];
                acc[i] = __builtin_amdgcn_mfma_f32_16x16x32_f16(af, bf, acc[i], 0, 0, 0);
            }
        }
        if (tap < 8) {
            #pragma unroll
            for (int pg = 0; pg < 2; pg++) {
                half4v wg = wgp[pg];
                half8v v = rr[pg][0] * bcast8(wg[0]) + rr[pg][1] * bcast8(wg[1])
                         + rr[pg][2] * bcast8(wg[2]) + rr[pg][3] * bcast8(wg[3]);
                *(half8v*)&s_T[(tap + 1) & 1][gpx0 + pg * 8][seg * 8] = v;
            }
        }
        __syncthreads();
    }

    // ================= epilogue (r9 verbatim) =================
    // acc[i]: col(m16) = o-in-tile (wave q owns o-tile q), row = px-in-tile i
    #pragma unroll
    for (int i = 0; i < 4; i++) {
        int o = q * 16 + m16;
        #pragma unroll
        for (int r = 0; r < 4; r++)
            s_out[o * 65 + i * 16 + quad * 4 + r] = acc[i][r];
    }
    __syncthreads();
    {
        float mm = s_mm[px];
        #pragma unroll
        for (int jj = 0; jj < 16; jj++) {
            int o = q * 16 + jj;
            out[(((size_t)b * O + o) * Ho + h) * Wo + w0 + px] =
                s_out[o * 65 + px] * mm + bias[o];
        }
    }
}

extern "C" void kernel_launch(void* const* d_in, const int* in_sizes, int n_in,
                              void* d_out, int out_size, void* d_ws, size_t ws_size,
                              hipStream_t stream) {
    const float* x        = (const float*)d_in[0];
    const float* weight   = (const float*)d_in[1];
    const float* bias     = (const float*)d_in[2];
    const float* offset_w = (const float*)d_in[3];
    const float* offset_b = (const float*)d_in[4];
    const float* mod_w    = (const float*)d_in[5];
    const float* mod_b    = (const float*)d_in[6];
    float* out = (float*)d_out;

    // Workspace (halves): wB 36,864 | wAB 18,432 | xh 4,194,304 (byte 110,592)
    _Float16* wB  = (_Float16*)d_ws;
    _Float16* wAB = wB + 36864;
    _Float16* xh  = wAB + 18432;

    prep_all<<<BB * H + 144, 256, 0, stream>>>(
        x, weight, offset_w, mod_w, xh, wB, wAB);

    int nblk = BB * Ho * (Wo / TILE);   // 1024
    fused_kernel<<<nblk, 256, 0, stream>>>(
        xh, wB, wAB, bias, offset_b, mod_b, out);
}